// Round 13
// baseline (369.024 us; speedup 1.0000x reference)
//
#include <hip/hip_runtime.h>
#include <hip/hip_bf16.h>

#define T_SEQ 512

typedef __attribute__((ext_vector_type(8))) short frag_ab;
typedef __attribute__((ext_vector_type(4))) float frag_cd;

static __device__ __forceinline__ unsigned short f2bf_rnd(float f){
    union { float f; unsigned u; } v; v.f = f;
    unsigned r = v.u + 0x7fffu + ((v.u >> 16) & 1u);
    return (unsigned short)(r >> 16);
}
static __device__ __forceinline__ float bf2f(unsigned short h){
    union { unsigned u; float f; } v; v.u = ((unsigned)h) << 16;
    return v.f;
}
static __device__ __forceinline__ float sigf(float v){
    return __builtin_amdgcn_rcpf(1.0f + __builtin_amdgcn_exp2f(-1.4426950408889634f * v));
}
static __device__ __forceinline__ float tanhf2(float v){
    return 2.0f * __builtin_amdgcn_rcpf(1.0f + __builtin_amdgcn_exp2f(-2.8853900817779268f * v)) - 1.0f;
}
static __device__ __forceinline__ frag_ab loadBfrag(const float* __restrict__ W, int ldk, int jcol, int k0){
    const float* p = W + jcol * ldk + k0;
    frag_ab r;
    #pragma unroll
    for (int i = 0; i < 8; ++i) r[i] = (short)f2bf_rnd(p[i]);
    return r;
}
static __device__ __forceinline__ frag_cd splat4(float v){ return frag_cd{v,v,v,v}; }

#define MFMA(a,b,c) __builtin_amdgcn_mfma_f32_16x16x32_bf16((a),(b),(c),0,0,0)
#define MEMFENCE() asm volatile("" ::: "memory")
#define LGKM0()    asm volatile("s_waitcnt lgkmcnt(0)" ::: "memory")

// R13: NO per-step s_barrier. Wave-specialized producer-consumer with LDS
// mailbox flags (monotonic step counters, int). Protocol:
//   L1(t): wait FL1[0..3]>=t-1, FXW[0..1]>=t-2, FL2[0..1]>=t-4
//          read x(t) [XHI slot t&3], h1(t-1) [RGhi slot (t-1)&3],
//          write h1(t) -> RGhi[t&3], drain, flag.
//   L2(t): wait FL1>=t, FL2[partner]>=t-1
//          read h1(t), h2(t-1) [H2HI slot (t-1)&1], write h2(t) -> [t&1], flag.
//   XW(t): wait FL1>=t-2; stage x(t+2) -> XHI[(t+2)&3], flag.
// Overwrite safety: L1 overwrites h1(t-4) (FL2>=t-4 guards L2; peers implied),
// XW overwrites x(t-2) (FL1>=t-2 guards), L2 overwrites h2(t-2) (partner>=t-1).
// Deadlock-free: each wait references a flag whose owner can always progress.
// Consumers poll BEFORE reading data (safe vs LDS pipe ordering); producers
// drain lgkmcnt between data write and flag write.
__global__ __launch_bounds__(512, 2)
void gru_fusedC(const float* __restrict__ x,
                const float* __restrict__ Wih1, const float* __restrict__ Whh1,
                const float* __restrict__ bih1, const float* __restrict__ bhh1,
                const float* __restrict__ Wih2, const float* __restrict__ Whh2,
                const float* __restrict__ bih2, const float* __restrict__ bhh2,
                const float* __restrict__ Wfc,  const float* __restrict__ bfc,
                const float* __restrict__ Wout, const float* __restrict__ bout,
                float* __restrict__ out)
{
    __shared__ __align__(16) unsigned short RGhi[4][288];   // h1 ring, depth 4
    __shared__ __align__(16) unsigned short XHI[4][288];    // x ring, depth 4
    __shared__ __align__(16) unsigned short H2HI[2][160];   // h2 ring, depth 2
    __shared__ int FLAGS[8];   // [0..3]=L1 wv, [4..5]=L2, [6..7]=XW
    __shared__ float HFIN[128];
    __shared__ float FCS[64];

    const int tid  = threadIdx.x;
    const int wv   = tid >> 6;
    const int lane = tid & 63;
    const int lrow = lane & 15;
    const int lq   = lane >> 4;
    const int b4   = lrow >> 2;          // A-frag row -> batch
    const int bbase = blockIdx.x * 4;
    const int hv   = (int)(blockIdx.x & 1);
    const bool isL1 = (wv < 4);
    const bool isL2 = (!isL1) && (((wv >> 1) & 1) == hv);
    const int mi   = wv & 1;             // index within L2/XW pair

    for (int i = tid; i < 288; i += 512){ RGhi[3][i] = 0; }
    for (int i = tid; i < 160; i += 512){ H2HI[1][i] = 0; }
    if (tid < 8) FLAGS[tid] = -1;

    // prologue x staging: x(0)->slot0, x(1)->slot1 (512 thr x 1 elem)
    {
        const int s = tid >> 8, idx = tid & 255;
        const int b = idx >> 6, k = idx & 63;
        XHI[s][b*72 + k] = f2bf_rnd(x[((size_t)(bbase + b) * T_SEQ + s) * 64 + k]);
    }

    // role-unioned persistent registers
    frag_ab WF[12];
    frag_cd BF[4];

    if (isL1){
        const int col1 = wv*16 + lrow;
        #pragma unroll
        for (int kf = 0; kf < 2; ++kf){
            const int k0 = kf*32 + 8*lq;
            WF[0+kf]  = loadBfrag(Wih1, 64, col1,       k0);
            WF[2+kf]  = loadBfrag(Wih1, 64, 64  + col1, k0);
            WF[4+kf]  = loadBfrag(Wih1, 64, 128 + col1, k0);
            WF[6+kf]  = loadBfrag(Whh1, 64, col1,       k0);
            WF[8+kf]  = loadBfrag(Whh1, 64, 64  + col1, k0);
            WF[10+kf] = loadBfrag(Whh1, 64, 128 + col1, k0);
        }
        BF[0] = splat4(bih1[col1] + bhh1[col1]);
        BF[1] = splat4(bih1[64 + col1] + bhh1[64 + col1]);
        BF[2] = splat4(bih1[128 + col1]);
        BF[3] = splat4(bhh1[128 + col1]);
    } else if (isL2){
        const int c2 = mi*16 + lrow;
        #pragma unroll
        for (int kf = 0; kf < 2; ++kf){
            const int k0 = kf*32 + 8*lq;
            WF[0+kf] = loadBfrag(Wih2, 64, c2,      k0);
            WF[2+kf] = loadBfrag(Wih2, 64, 32 + c2, k0);
            WF[4+kf] = loadBfrag(Wih2, 64, 64 + c2, k0);
        }
        WF[6] = loadBfrag(Whh2, 32, c2,      8*lq);
        WF[7] = loadBfrag(Whh2, 32, 32 + c2, 8*lq);
        WF[8] = loadBfrag(Whh2, 32, 64 + c2, 8*lq);
        BF[0] = splat4(bih2[c2] + bhh2[c2]);
        BF[1] = splat4(bih2[32 + c2] + bhh2[32 + c2]);
        BF[2] = splat4(bih2[64 + c2]);
        BF[3] = splat4(bhh2[64 + c2]);
    }

    // x staging setup (XW pair): 2 floats/thread, 2-step register hold
    const int u   = mi*64 + lane;
    const int xb2 = u >> 5, xk2 = (u & 31)*2;
    const int xo2 = xb2*72 + xk2;
    const float* xld = x + ((size_t)(bbase + xb2) * T_SEQ + 4)*64 + xk2;
    float2 xp0 = {0.f,0.f}, xp1 = {0.f,0.f};
    if (!isL1 && !isL2){
        xp0 = *(const float2*)(x + ((size_t)(bbase + xb2) * T_SEQ + 2)*64 + xk2);
        xp1 = *(const float2*)(x + ((size_t)(bbase + xb2) * T_SEQ + 3)*64 + xk2);
    }

    const int fo0 = b4*72 + 8*lq;
    const int go2 = b4*40 + 8*lq;
    const int rgo = lq*72 + (wv & 3)*16 + lrow;
    const int h2o = lq*40 + mi*16 + lrow;

    float hs = 0.f;

    __syncthreads();   // flags + prologue visible; last block-wide barrier

    volatile int* VF = FLAGS;

    if (isL1){
#define L1STEP(J) do{                                                         \
        const int t = tb + (J);                                               \
        while (VF[6] < t-2 || VF[7] < t-2) {}                                 \
        MEMFENCE();                                                           \
        const frag_ab xhf0 = *(const frag_ab*)(&XHI[J][fo0]);                 \
        const frag_ab xhf1 = *(const frag_ab*)(&XHI[J][fo0 + 32]);            \
        __builtin_amdgcn_s_setprio(1);                                        \
        frag_cd A0, A1, A2, A3;                                               \
        A0 = MFMA(xhf0, WF[0], BF[0]); A0 = MFMA(xhf1, WF[1], A0);            \
        A1 = MFMA(xhf0, WF[2], BF[1]); A1 = MFMA(xhf1, WF[3], A1);            \
        A2 = MFMA(xhf0, WF[4], BF[2]); A2 = MFMA(xhf1, WF[5], A2);            \
        __builtin_amdgcn_s_setprio(0);                                        \
        while (VF[0] < t-1 || VF[1] < t-1 || VF[2] < t-1 || VF[3] < t-1       \
            || VF[4] < t-4 || VF[5] < t-4) {}                                 \
        MEMFENCE();                                                           \
        const frag_ab hhf0 = *(const frag_ab*)(&RGhi[((J)+3)&3][fo0]);        \
        const frag_ab hhf1 = *(const frag_ab*)(&RGhi[((J)+3)&3][fo0 + 32]);   \
        __builtin_amdgcn_s_setprio(1);                                        \
        A0 = MFMA(hhf0, WF[6], A0);  A0 = MFMA(hhf1, WF[7], A0);              \
        A1 = MFMA(hhf0, WF[8], A1);  A1 = MFMA(hhf1, WF[9], A1);              \
        A3 = MFMA(hhf0, WF[10], BF[3]); A3 = MFMA(hhf1, WF[11], A3);          \
        __builtin_amdgcn_s_setprio(0);                                        \
        const float rg = sigf(A0[0]), zg = sigf(A1[0]);                       \
        const float ng = tanhf2(A2[0] + rg*A3[0]);                            \
        hs = ng + zg*(hs - ng);                                               \
        RGhi[J][rgo] = f2bf_rnd(hs);                                          \
        LGKM0();                                                              \
        if (lane == 0) VF[wv] = t;                                            \
}while(0)
        #pragma unroll 1
        for (int i = 0, tb = 0; i < 128; ++i, tb += 4){
            L1STEP(0); L1STEP(1); L1STEP(2); L1STEP(3);
        }
#undef L1STEP
    } else if (isL2){
        const int po = 4 + (mi ^ 1);
#define L2STEP(J) do{                                                         \
        const int t = tb + (J);                                               \
        while (VF[0] < t || VF[1] < t || VF[2] < t || VF[3] < t               \
            || VF[po] < t-1) {}                                               \
        MEMFENCE();                                                           \
        const frag_ab hhf0 = *(const frag_ab*)(&RGhi[J][fo0]);                \
        const frag_ab hhf1 = *(const frag_ab*)(&RGhi[J][fo0 + 32]);           \
        const frag_ab g2hf = *(const frag_ab*)(&H2HI[((J)+1)&1][go2]);        \
        __builtin_amdgcn_s_setprio(1);                                        \
        frag_cd B0, B1, B2, B3;                                               \
        B0 = MFMA(hhf0, WF[0], BF[0]); B0 = MFMA(hhf1, WF[1], B0);            \
        B0 = MFMA(g2hf, WF[6], B0);                                           \
        B1 = MFMA(hhf0, WF[2], BF[1]); B1 = MFMA(hhf1, WF[3], B1);            \
        B1 = MFMA(g2hf, WF[7], B1);                                           \
        B2 = MFMA(hhf0, WF[4], BF[2]); B2 = MFMA(hhf1, WF[5], B2);            \
        B3 = MFMA(g2hf, WF[8], BF[3]);                                        \
        __builtin_amdgcn_s_setprio(0);                                        \
        const float rv = sigf(B0[0]), zv = sigf(B1[0]);                       \
        const float nv = tanhf2(B2[0] + rv*B3[0]);                            \
        hs = nv + zv*(hs - nv);                                               \
        H2HI[(J)&1][h2o] = f2bf_rnd(hs);                                      \
        LGKM0();                                                              \
        if (lane == 0) VF[4+mi] = t;                                          \
}while(0)
        #pragma unroll 1
        for (int i = 0, tb = 0; i < 128; ++i, tb += 4){
            L2STEP(0); L2STEP(1); L2STEP(2); L2STEP(3);
        }
#undef L2STEP
    } else {
#define XWSTEP(J) do{                                                         \
        const int t = tb + (J);                                               \
        while (VF[0] < t-2 || VF[1] < t-2 || VF[2] < t-2 || VF[3] < t-2) {}   \
        MEMFENCE();                                                           \
        const float2 xn2 = *(const float2*)xld;                               \
        if (t < 507) xld += 64;                                               \
        const unsigned short a0 = f2bf_rnd(xp0.x), a1 = f2bf_rnd(xp0.y);      \
        *(unsigned*)(&XHI[((J)+2)&3][xo2]) = (unsigned)a0 | ((unsigned)a1 << 16); \
        xp0 = xp1; xp1 = xn2;                                                 \
        LGKM0();                                                              \
        if (lane == 0) VF[6+mi] = t;                                          \
}while(0)
        #pragma unroll 1
        for (int i = 0, tb = 0; i < 128; ++i, tb += 4){
            XWSTEP(0); XWSTEP(1); XWSTEP(2); XWSTEP(3);
        }
#undef XWSTEP
    }

    __syncthreads();

    // head: h2(511) in H2 slot 511&1 = 1
    if (tid < 128){
        const int r = tid >> 5, c = tid & 31;
        HFIN[r*32 + c] = bf2f(H2HI[1][r*40 + c]);
    }
    __syncthreads();
    if (tid < 64){
        const int b = tid >> 4, f = tid & 15;
        float s = bfc[f];
        #pragma unroll
        for (int k = 0; k < 32; ++k) s += HFIN[b*32 + k] * Wfc[f*32 + k];
        FCS[b*16 + f] = fmaxf(s, 0.f);
    }
    __syncthreads();
    if (tid < 4){
        float o = bout[0];
        #pragma unroll
        for (int f = 0; f < 16; ++f) o += FCS[tid*16 + f] * Wout[f];
        out[bbase + tid] = o;
    }
}

extern "C" void kernel_launch(void* const* d_in, const int* in_sizes, int n_in,
                              void* d_out, int out_size, void* d_ws, size_t ws_size,
                              hipStream_t stream) {
    const float* x    = (const float*)d_in[0];
    const float* Wih1 = (const float*)d_in[1];
    const float* Whh1 = (const float*)d_in[2];
    const float* bih1 = (const float*)d_in[3];
    const float* bhh1 = (const float*)d_in[4];
    const float* Wih2 = (const float*)d_in[5];
    const float* Whh2 = (const float*)d_in[6];
    const float* bih2 = (const float*)d_in[7];
    const float* bhh2 = (const float*)d_in[8];
    const float* Wfc  = (const float*)d_in[9];
    const float* bfc  = (const float*)d_in[10];
    const float* Wout = (const float*)d_in[11];
    const float* bout = (const float*)d_in[12];

    gru_fusedC<<<512, 512, 0, stream>>>(x, Wih1, Whh1, bih1, bhh1,
                                        Wih2, Whh2, bih2, bhh2,
                                        Wfc, bfc, Wout, bout, (float*)d_out);
}